// Round 8
// baseline (300.236 us; speedup 1.0000x reference)
//
#include <hip/hip_runtime.h>
#include <hip/hip_bf16.h>
#include <math.h>

// Problem constants
#define S_  512
#define D_  2048
#define HK_ 8
#define HV_ 16
#define DK_ 128
#define DV_ 128
#define KEY_DIM_ 1024
#define VAL_DIM_ 2048
#define QKVZ_N  6144
#define EPS_ 1e-6f
#define SPAD_ (S_ + 8)

typedef __attribute__((ext_vector_type(8))) short short8;
typedef __attribute__((ext_vector_type(4))) float f32x4;
typedef unsigned short ushort_t;
typedef unsigned int uint_t;

// ---------------------------------------------------------------------------
// helpers
// ---------------------------------------------------------------------------
__device__ __forceinline__ ushort_t f2bf(float x) {
    uint_t u = __float_as_uint(x);
    return (ushort_t)((u + 0x7FFFu + ((u >> 16) & 1u)) >> 16);
}

__device__ __forceinline__ void gl2lds16(const void* g, void* l) {
    __builtin_amdgcn_global_load_lds((const __attribute__((address_space(1))) uint_t*)g,
                                     (__attribute__((address_space(3))) uint_t*)l, 16, 0, 0);
}
__device__ __forceinline__ void gl2lds4(const void* g, void* l) {
    __builtin_amdgcn_global_load_lds((const __attribute__((address_space(1))) uint_t*)g,
                                     (__attribute__((address_space(3))) uint_t*)l, 4, 0, 0);
}

#define RL(x, l) __int_as_float(__builtin_amdgcn_readlane(__float_as_int(x), (l)))

// ---------------------------------------------------------------------------
// fused prep kernel: [0,1024) convert hidden->bf16 ; [1024,4096) transpose W_qkvz ;
// [4096,5120) transpose W_out ; [5120,5632) ba = hidden @ W_ba
// ---------------------------------------------------------------------------
__device__ __forceinline__ void transpose_body(const float* __restrict__ W,
                                               ushort_t* __restrict__ Th,
                                               int K, int N, int kb, int nb,
                                               int t, float* smem) {
    float (*tile)[65] = (float(*)[65])smem;
#pragma unroll
    for (int i = 0; i < 4; ++i) {
        int r = (t >> 4) + i * 16;
        int c4 = (t & 15) * 4;
        float4 v = *(const float4*)&W[(size_t)(kb + r) * N + nb + c4];
        tile[r][c4 + 0] = v.x; tile[r][c4 + 1] = v.y;
        tile[r][c4 + 2] = v.z; tile[r][c4 + 3] = v.w;
    }
    __syncthreads();
#pragma unroll
    for (int i = 0; i < 2; ++i) {
        int idx = t + 256 * i;
        int n = idx >> 3;
        int k8 = (idx & 7) * 8;
        ushort_t p[8];
#pragma unroll
        for (int r = 0; r < 8; ++r) p[r] = f2bf(tile[k8 + r][n]);
        *(uint4*)&Th[(size_t)(nb + n) * K + kb + k8] = *(const uint4*)p;
    }
}

__global__ __launch_bounds__(256) void prep_kernel(const float* __restrict__ hidden,
                                                   const float* __restrict__ W_qkvz,
                                                   const float* __restrict__ W_out,
                                                   const float* __restrict__ Wba,
                                                   ushort_t* __restrict__ hidh,
                                                   ushort_t* __restrict__ Wqh,
                                                   ushort_t* __restrict__ Woh,
                                                   float* __restrict__ ba) {
    __shared__ float smem[64 * 65];
    const int id = blockIdx.x;
    const int t = threadIdx.x;

    if (id < 1024) {                      // convert hidden -> bf16
        int i = id * 256 + t;
        float4 v = ((const float4*)hidden)[i];
        ushort4 h;
        h.x = f2bf(v.x); h.y = f2bf(v.y); h.z = f2bf(v.z); h.w = f2bf(v.w);
        ((ushort4*)hidh)[i] = h;
    } else if (id < 1024 + 3072) {        // W_qkvz [2048][6144] -> [6144][2048]
        int lid = id - 1024;
        transpose_body(W_qkvz, Wqh, D_, QKVZ_N, (lid / 96) * 64, (lid % 96) * 64, t, smem);
    } else if (id < 1024 + 3072 + 1024) { // W_out [2048][2048] -> [2048][2048]^T
        int lid = id - 4096;
        transpose_body(W_out, Woh, D_, D_, (lid / 32) * 64, (lid % 32) * 64, t, smem);
    } else {                              // ba
        const int s = id - 5120;
        const int j = t & 31;
        const int kg = t >> 5;
        const float* h = hidden + (size_t)s * D_;
        float sum = 0.f;
        const int k0 = kg * 256;
#pragma unroll 8
        for (int k = k0; k < k0 + 256; ++k)
            sum = fmaf(h[k], Wba[(size_t)k * 32 + j], sum);
        float (*red)[32] = (float(*)[32])smem;
        red[kg][j] = sum;
        __syncthreads();
        if (t < 32) {
            float tot = 0.f;
#pragma unroll
            for (int r = 0; r < 8; ++r) tot += red[r][j];
            ba[s * 32 + j] = tot;
        }
    }
}

// ---------------------------------------------------------------------------
// bf16 MFMA GEMM, m97 structure (unchanged)
// ---------------------------------------------------------------------------
template<int BM, int BN, int WR, int WC>
__global__ __launch_bounds__(256) void gemm_bf16(const ushort_t* __restrict__ A,
                                                 const ushort_t* __restrict__ B,
                                                 float* __restrict__ C,
                                                 int M, int N, int K) {
    constexpr int TM = BM / (16 * WR);
    constexpr int TN = BN / (16 * WC);
    constexpr int AI = (BM / 16) * 2;
    constexpr int BI = (BN / 16) * 2;

    __shared__ __align__(16) ushort_t sA[2][2][BM][32];
    __shared__ __align__(16) ushort_t sB[2][2][BN][32];

    const int t = threadIdx.x;
    const int w = t >> 6, lane = t & 63;
    const int wr = w / WC, wc = w % WC;
    const int lm = lane & 15, quad = lane >> 4;
    const int m0 = blockIdx.y * BM, n0 = blockIdx.x * BN;
    const int lrow = lane >> 2;
    const int lch  = (lane & 3) * 8;

    auto stage = [&](int buf, int k0) {
#pragma unroll
        for (int j = w; j < AI; j += 4) {
            int ks = j & 1, r0 = (j >> 1) * 16;
            gl2lds16(&A[(size_t)(m0 + r0 + lrow) * K + k0 + ks * 32 + lch],
                     &sA[buf][ks][r0][0]);
        }
#pragma unroll
        for (int j = w; j < BI; j += 4) {
            int ks = j & 1, r0 = (j >> 1) * 16;
            gl2lds16(&B[(size_t)(n0 + r0 + lrow) * K + k0 + ks * 32 + lch],
                     &sB[buf][ks][r0][0]);
        }
    };

    f32x4 acc[TM][TN] = {};
    stage(0, 0);
    __syncthreads();

    const int NK = K / 64;
    for (int it = 0; it < NK; ++it) {
        int buf = it & 1;
        if (it + 1 < NK) stage(buf ^ 1, (it + 1) * 64);
#pragma unroll
        for (int ks = 0; ks < 2; ++ks) {
            short8 bf[TN];
#pragma unroll
            for (int ni = 0; ni < TN; ++ni)
                bf[ni] = *(const short8*)&sB[buf][ks][wc * (TN * 16) + ni * 16 + lm][quad * 8];
#pragma unroll
            for (int mi = 0; mi < TM; ++mi) {
                short8 af = *(const short8*)&sA[buf][ks][wr * (TM * 16) + mi * 16 + lm][quad * 8];
#pragma unroll
                for (int ni = 0; ni < TN; ++ni)
                    acc[mi][ni] = __builtin_amdgcn_mfma_f32_16x16x32_bf16(af, bf[ni], acc[mi][ni], 0, 0, 0);
            }
        }
        __syncthreads();
    }

#pragma unroll
    for (int mi = 0; mi < TM; ++mi)
#pragma unroll
        for (int ni = 0; ni < TN; ++ni) {
            int row = m0 + wr * TM * 16 + mi * 16 + quad * 4;
            int col = n0 + wc * TN * 16 + ni * 16 + lm;
#pragma unroll
            for (int r = 0; r < 4; ++r)
                C[(size_t)(row + r) * N + col] = acc[mi][ni][r];
        }
}

// ---------------------------------------------------------------------------
// causal depthwise conv (K=4) + silu + l2norm (q/k). grid (S,32), block 128.
// ---------------------------------------------------------------------------
__global__ __launch_bounds__(128) void conv_kernel(const float* __restrict__ qkvz,
                                                   const float* __restrict__ conv_w,
                                                   float* __restrict__ qc,
                                                   float* __restrict__ kc,
                                                   float* __restrict__ vc) {
    const int s   = blockIdx.x;
    const int grp = blockIdx.y;
    const int d   = threadIdx.x;

    int col, c;
    if (grp < 8) {
        int hk = grp;
        col = hk * 768 + d;
        c   = hk * 128 + d;
    } else if (grp < 16) {
        int hk = grp - 8;
        col = hk * 768 + 128 + d;
        c   = 1024 + (hk * 128 + d);
    } else {
        int hv = grp - 16;
        col = (hv >> 1) * 768 + 256 + (hv & 1) * 128 + d;
        c   = 2048 + (hv * 128 + d);
    }

    const float w0 = conv_w[c * 4 + 0];
    const float w1 = conv_w[c * 4 + 1];
    const float w2 = conv_w[c * 4 + 2];
    const float w3 = conv_w[c * 4 + 3];

    float x = 0.f;
    if (s - 3 >= 0) x += qkvz[(size_t)(s - 3) * QKVZ_N + col] * w0;
    if (s - 2 >= 0) x += qkvz[(size_t)(s - 2) * QKVZ_N + col] * w1;
    if (s - 1 >= 0) x += qkvz[(size_t)(s - 1) * QKVZ_N + col] * w2;
    x += qkvz[(size_t)s * QKVZ_N + col] * w3;

    x = x / (1.f + expf(-x));

    if (grp < 16) {
        float ss = x * x;
#pragma unroll
        for (int m = 1; m < 64; m <<= 1) ss += __shfl_xor(ss, m);
        __shared__ float red[2];
        int wid = threadIdx.x >> 6;
        if ((threadIdx.x & 63) == 0) red[wid] = ss;
        __syncthreads();
        float tot = red[0] + red[1];
        float scale = rsqrtf(tot + EPS_);
        if (grp < 8) {
            x = x * scale * 0.08838834764831845f;   // * DK^-0.5
            qc[((size_t)s * HK_ + grp) * DK_ + d] = x;
        } else {
            x = x * scale;
            kc[((size_t)s * HK_ + (grp - 8)) * DK_ + d] = x;
        }
    } else {
        vc[((size_t)s * HV_ + (grp - 16)) * DV_ + d] = x;
    }
}

// ---------------------------------------------------------------------------
// cross-lane reductions
// ---------------------------------------------------------------------------
template<int CTRL>
__device__ __forceinline__ float dpp_xor(float x) {
    int v = __builtin_amdgcn_update_dpp(0, __float_as_int(x), CTRL, 0xF, 0xF, true);
    return __int_as_float(v);
}
__device__ __forceinline__ float red16(float x) {
    x += dpp_xor<0xB1>(x);
    x += dpp_xor<0x4E>(x);
    x += dpp_xor<0x141>(x);
    x += dpp_xor<0x140>(x);
    return x;
}
__device__ __forceinline__ float red32(float x) {
    x = red16(x);
    x += __int_as_float(__builtin_amdgcn_ds_swizzle(__float_as_int(x), 0x401F));
    return x;
}

__device__ __forceinline__ float gate_g(float a, float Aexp) {
    float sp = (a > 20.f) ? a : log1pf(expf(a));
    return expf(-Aexp * sp);
}

// ---------------------------------------------------------------------------
// scal_kernel: J=4 lookahead scalars (unchanged from R6)
// ---------------------------------------------------------------------------
__global__ __launch_bounds__(256) void scal_kernel(const float* __restrict__ kc,
                                                   const float* __restrict__ qc,
                                                   const float* __restrict__ ba,
                                                   const float* __restrict__ A_log,
                                                   const float* __restrict__ dt_bias,
                                                   float* __restrict__ scal) {
    const int t  = blockIdx.x;
    const int hk = threadIdx.x >> 5;
    const int l  = threadIdx.x & 31;

    const float* kt = &kc[((size_t)t * HK_ + hk) * DK_ + l * 4];
    const float* qt = &qc[((size_t)t * HK_ + hk) * DK_ + l * 4];
    const float4 zz = {0.f, 0.f, 0.f, 0.f};
    float4 k0 = *(const float4*)kt;
    float4 q0 = *(const float4*)qt;
    float4 k1 = (t >= 1) ? *(const float4*)(kt - (size_t)HK_ * DK_)     : zz;
    float4 k2 = (t >= 2) ? *(const float4*)(kt - (size_t)2 * HK_ * DK_) : zz;
    float4 k3 = (t >= 3) ? *(const float4*)(kt - (size_t)3 * HK_ * DK_) : zz;

    auto dot4 = [](float4 a, float4 b) { return a.x*b.x + a.y*b.y + a.z*b.z + a.w*b.w; };
    float c1 = red32(dot4(k0, k1));
    float c2 = red32(dot4(k0, k2));
    float c3 = red32(dot4(k0, k3));
    float d0 = red32(dot4(q0, k0));
    float d1 = red32(dot4(q0, k1));
    float d2 = red32(dot4(q0, k2));
    float d3 = red32(dot4(q0, k3));

    if (l < 2) {
        int h = hk * 2 + l;
        float Aexp = expf(A_log[h]);
        float dtb  = dt_bias[h];
        float bv = ba[t * 32 + hk * 4 + l];
        float av = ba[t * 32 + hk * 4 + 2 + l];
        float be = 1.f / (1.f + expf(-bv));
        float g0 = gate_g(av + dtb, Aexp);
        float g1 = 1.f, g2 = 1.f, g3 = 1.f;
        if (t >= 1) g1 = gate_g(ba[(t - 1) * 32 + hk * 4 + 2 + l] + dtb, Aexp);
        if (t >= 2) g2 = gate_g(ba[(t - 2) * 32 + hk * 4 + 2 + l] + dtb, Aexp);
        if (t >= 3) g3 = gate_g(ba[(t - 3) * 32 + hk * 4 + 2 + l] + dtb, Aexp);
        float G2 = g0 * g1, G3 = G2 * g2, G4 = G3 * g3;
        float4 oC = {g0, be, G4, 0.f};
        float4 oA = {-be * g0 * c1, -be * G2 * c2, -be * G3 * c3, -be * G4};
        float4 oB = {d0, g0 * d1, G2 * d2, G3 * d3};
        float* dst = &scal[(size_t)(h * SPAD_ + t) * 16];
        *(float4*)&dst[0]  = oC;
        *(float4*)&dst[4]  = oA;
        *(float4*)&dst[8]  = oB;
        *(float4*)&dst[12] = zz;
    }
}

// ---------------------------------------------------------------------------
// gated delta-rule scan, J=4 lookahead (R6/R7 algebra), ZERO-LDS version:
//  - k/q/v prefetched straight from global into 8-deep rotating register
//    slots (load-to-use distance 4-6 iters ~ 450+ cyc, covers L2/L3 latency;
//    compiler tracks exact vmcnt) — no LDS, no __syncthreads anywhere
//  - per-chunk scalars batch-loaded into lane registers, readlane per step
// grid (DV/4=32, HV=16) = 512 blocks x 64 thr (1 wave = 16 subs x 4 cols).
// thread rows {4sub..4sub+3, 64+4sub..+3}; 1 v-col per thread.
// ---------------------------------------------------------------------------
__global__ __launch_bounds__(64) void scan_kernel(const float* __restrict__ qc,
                                                  const float* __restrict__ kc,
                                                  const float* __restrict__ vc,
                                                  const float* __restrict__ scal,
                                                  float* __restrict__ core) {
    const int h = blockIdx.y, v0 = blockIdx.x * 4;
    const int lane = threadIdx.x;
    const int sub = lane & 15, colg = lane >> 4;
    const int v = v0 + colg;
    const int hk = h >> 1;

    f32x4 Sr[2] = {};                  // 8 state rows (4sub.., 64+4sub..) x 1 col
    f32x4 kR[8][2] = {}, qR[8][2] = {};
    float vR[8] = {};
    float U[4] = {}, V[4] = {}, dl[4] = {};
    float4 cur0 = {0,0,0,0}, cur1 = {0,0,0,0}, cur2 = {0,0,0,0};
    float4 nxt0 = {0,0,0,0}, nxt1 = {0,0,0,0}, nxt2 = {0,0,0,0};
    float4 prv0 = {0,0,0,0};

    // prologue: steps 0..5 into slots 0..5 (slots 6,7 = zeros = steps -2,-1)
#pragma unroll
    for (int p = 0; p < 6; ++p) {
        const size_t bo = ((size_t)p * HK_ + hk) * DK_;
        kR[p][0] = *(const f32x4*)&kc[bo + 4 * sub];
        kR[p][1] = *(const f32x4*)&kc[bo + 64 + 4 * sub];
        qR[p][0] = *(const f32x4*)&qc[bo + 4 * sub];
        qR[p][1] = *(const f32x4*)&qc[bo + 64 + 4 * sub];
        vR[p] = vc[((size_t)p * HV_ + h) * DV_ + v];
    }
    {
        const float* p = &scal[(size_t)(h * SPAD_ + (lane & 31)) * 16];
        cur0 = *(const float4*)p;
        cur1 = *(const float4*)(p + 4);
        cur2 = *(const float4*)(p + 8);
    }

    for (int c = 0; c < 16; ++c) {
        if (c + 1 < 16) {
            const float* p = &scal[(size_t)(h * SPAD_ + (c + 1) * 32 + (lane & 31)) * 16];
            nxt0 = *(const float4*)p;
            nxt1 = *(const float4*)(p + 4);
            nxt2 = *(const float4*)(p + 8);
        }
        const int t0 = c * 32;

#pragma unroll
        for (int j = 0; j < 32; ++j) {
            const int t = t0 + j;
            // 1. lazy S-update: apply step t-2 (uses k slot (j+6)&7, then freed)
            {
                const float g  = (j >= 2) ? RL(cur0.x, j - 2) : RL(prv0.x, 30 + j);
                const float dd = dl[(j + 2) & 3];
                const f32x4 g4 = {g, g, g, g};
                const f32x4 dd4 = {dd, dd, dd, dd};
                Sr[0] = kR[(j + 6) & 7][0] * dd4 + g4 * Sr[0];
                Sr[1] = kR[(j + 6) & 7][1] * dd4 + g4 * Sr[1];
            }
            // 2. global prefetch k/q/v for step t+6 into the just-freed slot
            {
                const size_t bo = ((size_t)(t + 6) * HK_ + hk) * DK_;
                kR[(j + 6) & 7][0] = *(const f32x4*)&kc[bo + 4 * sub];
                kR[(j + 6) & 7][1] = *(const f32x4*)&kc[bo + 64 + 4 * sub];
                qR[(j + 6) & 7][0] = *(const f32x4*)&qc[bo + 4 * sub];
                qR[(j + 6) & 7][1] = *(const f32x4*)&qc[bo + 64 + 4 * sub];
                vR[(j + 6) & 7] = vc[((size_t)(t + 6) * HV_ + h) * DV_ + v];
            }
            // 3. dots for step t+2 vs Sr (4-stale); 2 iters of reduction slack
            {
                f32x4 ku = kR[(j + 2) & 7][0] * Sr[0] + kR[(j + 2) & 7][1] * Sr[1];
                f32x4 qu = qR[(j + 2) & 7][0] * Sr[0] + qR[(j + 2) & 7][1] * Sr[1];
                U[(j + 2) & 3] = red16((ku[0] + ku[1]) + (ku[2] + ku[3]));
                V[(j + 2) & 3] = red16((qu[0] + qu[1]) + (qu[2] + qu[3]));
            }
            // 4. delta_t (1-fma chain) and o_t — scalars via readlane(lane j)
            {
                const float be = RL(cur0.y, j), G4 = RL(cur0.z, j);
                const float a1 = RL(cur1.x, j), a2 = RL(cur1.y, j);
                const float a3 = RL(cur1.z, j), bU = RL(cur1.w, j);
                const float w0 = RL(cur2.x, j), w1 = RL(cur2.y, j);
                const float w2 = RL(cur2.z, j), w3 = RL(cur2.w, j);
                const float d1 = dl[(j + 3) & 3], d2 = dl[(j + 2) & 3], d3 = dl[(j + 1) & 3];
                const float E = fmaf(bU, U[j & 3], be * vR[j & 7]);
                const float X = fmaf(a2, d2, fmaf(a3, d3, E));
                const float dn = fmaf(a1, d1, X);
                const float o = fmaf(w0, dn, fmaf(w1, d1,
                                  fmaf(w2, d2, fmaf(w3, d3, G4 * V[j & 3]))));
                if (sub == 0)
                    core[((size_t)t * HV_ + h) * DV_ + v] = o;
                dl[j & 3] = dn;
            }
        }
        prv0 = cur0;
        cur0 = nxt0; cur1 = nxt1; cur2 = nxt2;
    }
}

// ---------------------------------------------------------------------------
// RMS-norm + silu(z) gate -> bf16 (feeds gemm2 as A)
// ---------------------------------------------------------------------------
__global__ __launch_bounds__(128) void normgate_kernel(const float* __restrict__ core,
                                                       const float* __restrict__ qkvz,
                                                       const float* __restrict__ nw,
                                                       ushort_t* __restrict__ nh) {
    const int s  = blockIdx.x;
    const int hv = blockIdx.y;
    const int d  = threadIdx.x;

    float x = core[((size_t)s * HV_ + hv) * DV_ + d];
    float ss = x * x;
#pragma unroll
    for (int m = 1; m < 64; m <<= 1) ss += __shfl_xor(ss, m);
    __shared__ float red[2];
    int wid = threadIdx.x >> 6;
    if ((threadIdx.x & 63) == 0) red[wid] = ss;
    __syncthreads();
    float var = (red[0] + red[1]) * (1.f / 128.f);
    float rs  = rsqrtf(var + EPS_);

    float z  = qkvz[(size_t)s * QKVZ_N + (hv >> 1) * 768 + 512 + (hv & 1) * 128 + d];
    float sz = z / (1.f + expf(-z));

    float y = x * rs * nw[d] * sz;
    nh[(size_t)s * VAL_DIM_ + hv * DV_ + d] = f2bf(y);
}

// ---------------------------------------------------------------------------
// launch
// ---------------------------------------------------------------------------
extern "C" void kernel_launch(void* const* d_in, const int* in_sizes, int n_in,
                              void* d_out, int out_size, void* d_ws, size_t ws_size,
                              hipStream_t stream) {
    const float* hidden  = (const float*)d_in[0];
    const float* W_qkvz  = (const float*)d_in[1];
    const float* W_ba    = (const float*)d_in[2];
    const float* conv_w  = (const float*)d_in[3];
    const float* dt_bias = (const float*)d_in[4];
    const float* A_log   = (const float*)d_in[5];
    const float* norm_w  = (const float*)d_in[6];
    const float* W_out   = (const float*)d_in[7];
    float* out = (float*)d_out;

    char* w = (char*)d_ws;
    auto alloc = [&](size_t bytes) { char* p = w; w += (bytes + 255) & ~(size_t)255; return p; };

    float*    qkvz = (float*)alloc((size_t)S_ * QKVZ_N * 4);
    float*    ba   = (float*)alloc((size_t)S_ * 32 * 4);
    float*    qc   = (float*)alloc((size_t)SPAD_ * KEY_DIM_ * 4);
    float*    kc   = (float*)alloc((size_t)SPAD_ * KEY_DIM_ * 4);
    float*    vc   = (float*)alloc((size_t)SPAD_ * VAL_DIM_ * 4);
    float*    scal = (float*)alloc((size_t)HV_ * SPAD_ * 16 * 4);
    float*    core = (float*)alloc((size_t)S_ * VAL_DIM_ * 4);
    ushort_t* hidh = (ushort_t*)alloc((size_t)S_ * D_ * 2);
    ushort_t* nrmh = (ushort_t*)alloc((size_t)S_ * VAL_DIM_ * 2);
    ushort_t* Wqh  = (ushort_t*)alloc((size_t)D_ * QKVZ_N * 2);
    ushort_t* Woh  = (ushort_t*)alloc((size_t)VAL_DIM_ * D_ * 2);

    // 0. fused prep: hidden->bf16, both weight transposes, ba
    prep_kernel<<<dim3(5632), 256, 0, stream>>>(hidden, W_qkvz, W_out, W_ba,
                                                hidh, Wqh, Woh, ba);

    // 1. qkvz = hidden @ W_qkvz
    gemm_bf16<64, 128, 1, 4><<<dim3(QKVZ_N / 128, S_ / 64), 256, 0, stream>>>(
        hidh, Wqh, qkvz, S_, QKVZ_N, D_);

    // 2. conv + silu + l2norm
    conv_kernel<<<dim3(S_, 32), 128, 0, stream>>>(qkvz, conv_w, qc, kc, vc);

    // 3. lookahead scalars (gating fused)
    scal_kernel<<<dim3(S_), 256, 0, stream>>>(kc, qc, ba, A_log, dt_bias, scal);

    // 4. scan (J=4 lookahead; zero-LDS, barrier-free, global register prefetch)
    scan_kernel<<<dim3(DV_ / 4, HV_), 64, 0, stream>>>(qc, kc, vc, scal, core);

    // 5. RMS norm + gate -> bf16
    normgate_kernel<<<dim3(S_, HV_), 128, 0, stream>>>(core, qkvz, norm_w, nrmh);

    // 6. out = nrm @ W_out
    gemm_bf16<64, 64, 2, 2><<<dim3(D_ / 64, S_ / 64), 256, 0, stream>>>(
        nrmh, Woh, out, S_, D_, VAL_DIM_);
}

// Round 9
// 292.822 us; speedup vs baseline: 1.0253x; 1.0253x over previous
//
#include <hip/hip_runtime.h>
#include <hip/hip_bf16.h>
#include <math.h>

// Problem constants
#define S_  512
#define D_  2048
#define HK_ 8
#define HV_ 16
#define DK_ 128
#define DV_ 128
#define KEY_DIM_ 1024
#define VAL_DIM_ 2048
#define QKVZ_N  6144
#define EPS_ 1e-6f
#define SPAD_ (S_ + 8)

typedef __attribute__((ext_vector_type(8))) short short8;
typedef __attribute__((ext_vector_type(4))) float f32x4;
typedef unsigned short ushort_t;
typedef unsigned int uint_t;

// ---------------------------------------------------------------------------
// helpers
// ---------------------------------------------------------------------------
__device__ __forceinline__ ushort_t f2bf(float x) {
    uint_t u = __float_as_uint(x);
    return (ushort_t)((u + 0x7FFFu + ((u >> 16) & 1u)) >> 16);
}

__device__ __forceinline__ void gl2lds16(const void* g, void* l) {
    __builtin_amdgcn_global_load_lds((const __attribute__((address_space(1))) uint_t*)g,
                                     (__attribute__((address_space(3))) uint_t*)l, 16, 0, 0);
}
__device__ __forceinline__ void gl2lds4(const void* g, void* l) {
    __builtin_amdgcn_global_load_lds((const __attribute__((address_space(1))) uint_t*)g,
                                     (__attribute__((address_space(3))) uint_t*)l, 4, 0, 0);
}

// ---------------------------------------------------------------------------
// fused prep kernel: [0,1024) convert hidden->bf16 ; [1024,4096) transpose W_qkvz ;
// [4096,5120) transpose W_out ; [5120,5632) ba = hidden @ W_ba
// ---------------------------------------------------------------------------
__device__ __forceinline__ void transpose_body(const float* __restrict__ W,
                                               ushort_t* __restrict__ Th,
                                               int K, int N, int kb, int nb,
                                               int t, float* smem) {
    float (*tile)[65] = (float(*)[65])smem;
#pragma unroll
    for (int i = 0; i < 4; ++i) {
        int r = (t >> 4) + i * 16;
        int c4 = (t & 15) * 4;
        float4 v = *(const float4*)&W[(size_t)(kb + r) * N + nb + c4];
        tile[r][c4 + 0] = v.x; tile[r][c4 + 1] = v.y;
        tile[r][c4 + 2] = v.z; tile[r][c4 + 3] = v.w;
    }
    __syncthreads();
#pragma unroll
    for (int i = 0; i < 2; ++i) {
        int idx = t + 256 * i;
        int n = idx >> 3;
        int k8 = (idx & 7) * 8;
        ushort_t p[8];
#pragma unroll
        for (int r = 0; r < 8; ++r) p[r] = f2bf(tile[k8 + r][n]);
        *(uint4*)&Th[(size_t)(nb + n) * K + kb + k8] = *(const uint4*)p;
    }
}

__global__ __launch_bounds__(256) void prep_kernel(const float* __restrict__ hidden,
                                                   const float* __restrict__ W_qkvz,
                                                   const float* __restrict__ W_out,
                                                   const float* __restrict__ Wba,
                                                   ushort_t* __restrict__ hidh,
                                                   ushort_t* __restrict__ Wqh,
                                                   ushort_t* __restrict__ Woh,
                                                   float* __restrict__ ba) {
    __shared__ float smem[64 * 65];
    const int id = blockIdx.x;
    const int t = threadIdx.x;

    if (id < 1024) {                      // convert hidden -> bf16
        int i = id * 256 + t;
        float4 v = ((const float4*)hidden)[i];
        ushort4 h;
        h.x = f2bf(v.x); h.y = f2bf(v.y); h.z = f2bf(v.z); h.w = f2bf(v.w);
        ((ushort4*)hidh)[i] = h;
    } else if (id < 1024 + 3072) {        // W_qkvz [2048][6144] -> [6144][2048]
        int lid = id - 1024;
        transpose_body(W_qkvz, Wqh, D_, QKVZ_N, (lid / 96) * 64, (lid % 96) * 64, t, smem);
    } else if (id < 1024 + 3072 + 1024) { // W_out [2048][2048] -> [2048][2048]^T
        int lid = id - 4096;
        transpose_body(W_out, Woh, D_, D_, (lid / 32) * 64, (lid % 32) * 64, t, smem);
    } else {                              // ba
        const int s = id - 5120;
        const int j = t & 31;
        const int kg = t >> 5;
        const float* h = hidden + (size_t)s * D_;
        float sum = 0.f;
        const int k0 = kg * 256;
#pragma unroll 8
        for (int k = k0; k < k0 + 256; ++k)
            sum = fmaf(h[k], Wba[(size_t)k * 32 + j], sum);
        float (*red)[32] = (float(*)[32])smem;
        red[kg][j] = sum;
        __syncthreads();
        if (t < 32) {
            float tot = 0.f;
#pragma unroll
            for (int r = 0; r < 8; ++r) tot += red[r][j];
            ba[s * 32 + j] = tot;
        }
    }
}

// ---------------------------------------------------------------------------
// bf16 MFMA GEMM, m97 structure (unchanged)
// ---------------------------------------------------------------------------
template<int BM, int BN, int WR, int WC>
__global__ __launch_bounds__(256) void gemm_bf16(const ushort_t* __restrict__ A,
                                                 const ushort_t* __restrict__ B,
                                                 float* __restrict__ C,
                                                 int M, int N, int K) {
    constexpr int TM = BM / (16 * WR);
    constexpr int TN = BN / (16 * WC);
    constexpr int AI = (BM / 16) * 2;
    constexpr int BI = (BN / 16) * 2;

    __shared__ __align__(16) ushort_t sA[2][2][BM][32];
    __shared__ __align__(16) ushort_t sB[2][2][BN][32];

    const int t = threadIdx.x;
    const int w = t >> 6, lane = t & 63;
    const int wr = w / WC, wc = w % WC;
    const int lm = lane & 15, quad = lane >> 4;
    const int m0 = blockIdx.y * BM, n0 = blockIdx.x * BN;
    const int lrow = lane >> 2;
    const int lch  = (lane & 3) * 8;

    auto stage = [&](int buf, int k0) {
#pragma unroll
        for (int j = w; j < AI; j += 4) {
            int ks = j & 1, r0 = (j >> 1) * 16;
            gl2lds16(&A[(size_t)(m0 + r0 + lrow) * K + k0 + ks * 32 + lch],
                     &sA[buf][ks][r0][0]);
        }
#pragma unroll
        for (int j = w; j < BI; j += 4) {
            int ks = j & 1, r0 = (j >> 1) * 16;
            gl2lds16(&B[(size_t)(n0 + r0 + lrow) * K + k0 + ks * 32 + lch],
                     &sB[buf][ks][r0][0]);
        }
    };

    f32x4 acc[TM][TN] = {};
    stage(0, 0);
    __syncthreads();

    const int NK = K / 64;
    for (int it = 0; it < NK; ++it) {
        int buf = it & 1;
        if (it + 1 < NK) stage(buf ^ 1, (it + 1) * 64);
#pragma unroll
        for (int ks = 0; ks < 2; ++ks) {
            short8 bf[TN];
#pragma unroll
            for (int ni = 0; ni < TN; ++ni)
                bf[ni] = *(const short8*)&sB[buf][ks][wc * (TN * 16) + ni * 16 + lm][quad * 8];
#pragma unroll
            for (int mi = 0; mi < TM; ++mi) {
                short8 af = *(const short8*)&sA[buf][ks][wr * (TM * 16) + mi * 16 + lm][quad * 8];
#pragma unroll
                for (int ni = 0; ni < TN; ++ni)
                    acc[mi][ni] = __builtin_amdgcn_mfma_f32_16x16x32_bf16(af, bf[ni], acc[mi][ni], 0, 0, 0);
            }
        }
        __syncthreads();
    }

#pragma unroll
    for (int mi = 0; mi < TM; ++mi)
#pragma unroll
        for (int ni = 0; ni < TN; ++ni) {
            int row = m0 + wr * TM * 16 + mi * 16 + quad * 4;
            int col = n0 + wc * TN * 16 + ni * 16 + lm;
#pragma unroll
            for (int r = 0; r < 4; ++r)
                C[(size_t)(row + r) * N + col] = acc[mi][ni][r];
        }
}

// ---------------------------------------------------------------------------
// causal depthwise conv (K=4) + silu + l2norm (q/k). grid (S,32), block 128.
// ---------------------------------------------------------------------------
__global__ __launch_bounds__(128) void conv_kernel(const float* __restrict__ qkvz,
                                                   const float* __restrict__ conv_w,
                                                   float* __restrict__ qc,
                                                   float* __restrict__ kc,
                                                   float* __restrict__ vc) {
    const int s   = blockIdx.x;
    const int grp = blockIdx.y;
    const int d   = threadIdx.x;

    int col, c;
    if (grp < 8) {
        int hk = grp;
        col = hk * 768 + d;
        c   = hk * 128 + d;
    } else if (grp < 16) {
        int hk = grp - 8;
        col = hk * 768 + 128 + d;
        c   = 1024 + (hk * 128 + d);
    } else {
        int hv = grp - 16;
        col = (hv >> 1) * 768 + 256 + (hv & 1) * 128 + d;
        c   = 2048 + (hv * 128 + d);
    }

    const float w0 = conv_w[c * 4 + 0];
    const float w1 = conv_w[c * 4 + 1];
    const float w2 = conv_w[c * 4 + 2];
    const float w3 = conv_w[c * 4 + 3];

    float x = 0.f;
    if (s - 3 >= 0) x += qkvz[(size_t)(s - 3) * QKVZ_N + col] * w0;
    if (s - 2 >= 0) x += qkvz[(size_t)(s - 2) * QKVZ_N + col] * w1;
    if (s - 1 >= 0) x += qkvz[(size_t)(s - 1) * QKVZ_N + col] * w2;
    x += qkvz[(size_t)s * QKVZ_N + col] * w3;

    x = x / (1.f + expf(-x));

    if (grp < 16) {
        float ss = x * x;
#pragma unroll
        for (int m = 1; m < 64; m <<= 1) ss += __shfl_xor(ss, m);
        __shared__ float red[2];
        int wid = threadIdx.x >> 6;
        if ((threadIdx.x & 63) == 0) red[wid] = ss;
        __syncthreads();
        float tot = red[0] + red[1];
        float scale = rsqrtf(tot + EPS_);
        if (grp < 8) {
            x = x * scale * 0.08838834764831845f;   // * DK^-0.5
            qc[((size_t)s * HK_ + grp) * DK_ + d] = x;
        } else {
            x = x * scale;
            kc[((size_t)s * HK_ + (grp - 8)) * DK_ + d] = x;
        }
    } else {
        vc[((size_t)s * HV_ + (grp - 16)) * DV_ + d] = x;
    }
}

// ---------------------------------------------------------------------------
// cross-lane reductions
// ---------------------------------------------------------------------------
template<int CTRL>
__device__ __forceinline__ float dpp_xor(float x) {
    int v = __builtin_amdgcn_update_dpp(0, __float_as_int(x), CTRL, 0xF, 0xF, true);
    return __int_as_float(v);
}
__device__ __forceinline__ float red16(float x) {
    x += dpp_xor<0xB1>(x);
    x += dpp_xor<0x4E>(x);
    x += dpp_xor<0x141>(x);
    x += dpp_xor<0x140>(x);
    return x;
}
__device__ __forceinline__ float red32(float x) {
    x = red16(x);
    x += __int_as_float(__builtin_amdgcn_ds_swizzle(__float_as_int(x), 0x401F));
    return x;
}

__device__ __forceinline__ float gate_g(float a, float Aexp) {
    float sp = (a > 20.f) ? a : log1pf(expf(a));
    return expf(-Aexp * sp);
}

// ---------------------------------------------------------------------------
// scal_kernel: J=4 lookahead scalars (unchanged from R6)
// ---------------------------------------------------------------------------
__global__ __launch_bounds__(256) void scal_kernel(const float* __restrict__ kc,
                                                   const float* __restrict__ qc,
                                                   const float* __restrict__ ba,
                                                   const float* __restrict__ A_log,
                                                   const float* __restrict__ dt_bias,
                                                   float* __restrict__ scal) {
    const int t  = blockIdx.x;
    const int hk = threadIdx.x >> 5;
    const int l  = threadIdx.x & 31;

    const float* kt = &kc[((size_t)t * HK_ + hk) * DK_ + l * 4];
    const float* qt = &qc[((size_t)t * HK_ + hk) * DK_ + l * 4];
    const float4 zz = {0.f, 0.f, 0.f, 0.f};
    float4 k0 = *(const float4*)kt;
    float4 q0 = *(const float4*)qt;
    float4 k1 = (t >= 1) ? *(const float4*)(kt - (size_t)HK_ * DK_)     : zz;
    float4 k2 = (t >= 2) ? *(const float4*)(kt - (size_t)2 * HK_ * DK_) : zz;
    float4 k3 = (t >= 3) ? *(const float4*)(kt - (size_t)3 * HK_ * DK_) : zz;

    auto dot4 = [](float4 a, float4 b) { return a.x*b.x + a.y*b.y + a.z*b.z + a.w*b.w; };
    float c1 = red32(dot4(k0, k1));
    float c2 = red32(dot4(k0, k2));
    float c3 = red32(dot4(k0, k3));
    float d0 = red32(dot4(q0, k0));
    float d1 = red32(dot4(q0, k1));
    float d2 = red32(dot4(q0, k2));
    float d3 = red32(dot4(q0, k3));

    if (l < 2) {
        int h = hk * 2 + l;
        float Aexp = expf(A_log[h]);
        float dtb  = dt_bias[h];
        float bv = ba[t * 32 + hk * 4 + l];
        float av = ba[t * 32 + hk * 4 + 2 + l];
        float be = 1.f / (1.f + expf(-bv));
        float g0 = gate_g(av + dtb, Aexp);
        float g1 = 1.f, g2 = 1.f, g3 = 1.f;
        if (t >= 1) g1 = gate_g(ba[(t - 1) * 32 + hk * 4 + 2 + l] + dtb, Aexp);
        if (t >= 2) g2 = gate_g(ba[(t - 2) * 32 + hk * 4 + 2 + l] + dtb, Aexp);
        if (t >= 3) g3 = gate_g(ba[(t - 3) * 32 + hk * 4 + 2 + l] + dtb, Aexp);
        float G2 = g0 * g1, G3 = G2 * g2, G4 = G3 * g3;
        float4 oC = {g0, be, G4, 0.f};
        float4 oA = {-be * g0 * c1, -be * G2 * c2, -be * G3 * c3, -be * G4};
        float4 oB = {d0, g0 * d1, G2 * d2, G3 * d3};
        float* dst = &scal[(size_t)(h * SPAD_ + t) * 16];
        *(float4*)&dst[0]  = oC;
        *(float4*)&dst[4]  = oA;
        *(float4*)&dst[8]  = oB;
        *(float4*)&dst[12] = zz;
    }
}

// ---------------------------------------------------------------------------
// gated delta-rule scan, J=4 lookahead — R6 structure (measured best, 81.7us)
// with R7's conflict-free row partition:
//   thread rows {4sub..4sub+3, 64+4sub..64+4sub+3} -> b128 LDS reads,
//   16 lanes hit banks 4s..4s+3 (2-way alias only = free, m136)
// grid (DV/8=16, HV=16); block = 128 thr (2 waves x 4 cols); 1 col/thread.
// ---------------------------------------------------------------------------
__global__ __launch_bounds__(128) void scan_kernel(const float* __restrict__ qc,
                                                   const float* __restrict__ kc,
                                                   const float* __restrict__ vc,
                                                   const float* __restrict__ scal,
                                                   float* __restrict__ core) {
    const int h = blockIdx.y, v0 = blockIdx.x * 8;
    const int tid = threadIdx.x;
    const int w = tid >> 6, lane = tid & 63;
    const int sub = lane & 15, colg = lane >> 4;
    const int vloc = w * 4 + colg;
    const int v = v0 + vloc;
    const int hk = h >> 1;

    __shared__ __align__(16) float skq[2][32][256];  // [step][k(128)|q(128)]
    __shared__ __align__(16) float sv[2][32][8];
    __shared__ __align__(16) float ssc[2][32][16];
    __shared__ __align__(16) float hkq[2][4][256];   // head: first 4 steps of chunk
    __shared__ __align__(16) float hv[2][4][8];
    __shared__ __align__(16) float hsc[2][4][16];

    auto stage_chunk = [&](int buf, int c) {
        const int t0 = c * 32;
        for (int j = w * 16; j < w * 16 + 16; ++j) {
            int tt = t0 + j;
            const float* src = (lane < 32)
                ? &kc[((size_t)tt * HK_ + hk) * DK_ + lane * 4]
                : &qc[((size_t)tt * HK_ + hk) * DK_ + (lane - 32) * 4];
            gl2lds16(src, &skq[buf][j][0]);
        }
        if (w == 0) {
#pragma unroll
            for (int i = 0; i < 4; ++i) {
                int tt = t0 + i * 8 + (lane >> 3);
                gl2lds4(&vc[((size_t)tt * HV_ + h) * DV_ + v0 + (lane & 7)],
                        &sv[buf][i * 8][0]);
            }
        } else {
#pragma unroll
            for (int i = 0; i < 2; ++i)
                gl2lds16(&scal[(size_t)(h * SPAD_ + t0) * 16 + i * 256 + lane * 4],
                         &ssc[buf][i * 16][0]);
        }
    };
    auto stage_head = [&](int c) {   // head slot for chunk c = c&1
        const int hb = c & 1;
        const int t0 = c * 32;
        if (w == 1) {
#pragma unroll
            for (int j = 0; j < 4; ++j) {
                int tt = t0 + j;
                const float* src = (lane < 32)
                    ? &kc[((size_t)tt * HK_ + hk) * DK_ + lane * 4]
                    : &qc[((size_t)tt * HK_ + hk) * DK_ + (lane - 32) * 4];
                gl2lds16(src, &hkq[hb][j][0]);
            }
        } else {
            if (lane < 32)
                gl2lds4(&vc[((size_t)(t0 + (lane >> 3)) * HV_ + h) * DV_ + v0 + (lane & 7)],
                        &hv[hb][0][0]);
            if (lane < 16)
                gl2lds16(&scal[(size_t)(h * SPAD_ + t0) * 16 + lane * 4],
                         &hsc[hb][0][0]);
        }
    };

    // pipeline registers (slot indices compile-time after unroll)
    f32x4 Sr[2] = {};                     // 8 rows {4s..,64+4s..} x 1 col
    f32x4 kR[8][2] = {};                  // k slots, step&7 (lifetime 6)
    f32x4 qR[4][2] = {};                  // q slots, step&3
    float vR[4] = {};
    float4 scA[4] = {}, scB[4] = {}, scC[4] = {};
    float U[4] = {}, V[4] = {}, dl[4] = {};

    stage_chunk(0, 0);
    stage_head(1);
    __syncthreads();

    // prologue: kq for steps 0..3, scal/v for steps 0,1.
#pragma unroll
    for (int p = 0; p < 4; ++p) {
        kR[p][0] = *(const f32x4*)&skq[0][p][4 * sub];
        kR[p][1] = *(const f32x4*)&skq[0][p][64 + 4 * sub];
        qR[p][0] = *(const f32x4*)&skq[0][p][128 + 4 * sub];
        qR[p][1] = *(const f32x4*)&skq[0][p][192 + 4 * sub];
    }
#pragma unroll
    for (int p = 0; p < 2; ++p) {
        scC[p] = *(const float4*)&ssc[0][p][0];
        scA[p] = *(const float4*)&ssc[0][p][4];
        scB[p] = *(const float4*)&ssc[0][p][8];
        vR[p] = sv[0][p][vloc];
    }

    for (int c = 0; c < 16; ++c) {
        const int buf = c & 1;
        const int hb = (c + 1) & 1;      // head data for chunk c+1 (staged at c-1)
        if (c + 1 < 16) stage_chunk(buf ^ 1, c + 1);
        if (c + 2 < 16) stage_head(c + 2);
        const int t0 = c * 32;

#pragma unroll
        for (int j = 0; j < 32; ++j) {
            // 1. lazy S-update: apply step j-2 (zeros at start)
            {
                const float g  = ((const float*)&scC[(j + 2) & 3])[0];
                const float dd = dl[(j + 2) & 3];
                const f32x4 g4 = {g, g, g, g};
                const f32x4 dd4 = {dd, dd, dd, dd};
                Sr[0] = kR[(j + 6) & 7][0] * dd4 + g4 * Sr[0];
                Sr[1] = kR[(j + 6) & 7][1] * dd4 + g4 * Sr[1];
            }
            // 2. prefetch k/q for step j+4 (head region for j>=28)
            {
                const float* kb = (j < 28) ? &skq[buf][j + 4][0] : &hkq[hb][j - 28][0];
                kR[(j + 4) & 7][0] = *(const f32x4*)&kb[4 * sub];
                kR[(j + 4) & 7][1] = *(const f32x4*)&kb[64 + 4 * sub];
                qR[(j + 4) & 3][0] = *(const f32x4*)&kb[128 + 4 * sub];
                qR[(j + 4) & 3][1] = *(const f32x4*)&kb[192 + 4 * sub];
            }
            // 3. prefetch scal/v for step j+2 (head region for j>=30)
            {
                const float* sb = (j < 30) ? &ssc[buf][j + 2][0] : &hsc[hb][j - 30][0];
                scC[(j + 2) & 3] = *(const float4*)&sb[0];
                scA[(j + 2) & 3] = *(const float4*)&sb[4];
                scB[(j + 2) & 3] = *(const float4*)&sb[8];
                const float* vb = (j < 30) ? &sv[buf][j + 2][0] : &hv[hb][j - 30][0];
                vR[(j + 2) & 3] = vb[vloc];
            }
            // 4. dots for step j+2 vs Sr (4-stale); 2 iters of reduction slack
            {
                f32x4 ku = kR[(j + 2) & 7][0] * Sr[0] + kR[(j + 2) & 7][1] * Sr[1];
                f32x4 qu = qR[(j + 2) & 3][0] * Sr[0] + qR[(j + 2) & 3][1] * Sr[1];
                U[(j + 2) & 3] = red16((ku[0] + ku[1]) + (ku[2] + ku[3]));
                V[(j + 2) & 3] = red16((qu[0] + qu[1]) + (qu[2] + qu[3]));
            }
            // 5. delta_j (1-fma chain) and o_j
            {
                const float4 A = scA[j & 3], B = scB[j & 3], Cc = scC[j & 3];
                const float d1 = dl[(j + 3) & 3], d2 = dl[(j + 2) & 3], d3 = dl[(j + 1) & 3];
                const float E = fmaf(A.w, U[j & 3], Cc.y * vR[j & 3]);
                const float X = fmaf(A.y, d2, fmaf(A.z, d3, E));
                const float dn = fmaf(A.x, d1, X);
                const float o = fmaf(B.x, dn, fmaf(B.y, d1,
                                  fmaf(B.z, d2, fmaf(B.w, d3, Cc.z * V[j & 3]))));
                if (sub == 0)
                    core[((size_t)(t0 + j) * HV_ + h) * DV_ + v] = o;
                dl[j & 3] = dn;
            }
        }
        __syncthreads();
    }
}

// ---------------------------------------------------------------------------
// RMS-norm + silu(z) gate -> bf16 (feeds gemm2 as A)
// ---------------------------------------------------------------------------
__global__ __launch_bounds__(128) void normgate_kernel(const float* __restrict__ core,
                                                       const float* __restrict__ qkvz,
                                                       const float* __restrict__ nw,
                                                       ushort_t* __restrict__ nh) {
    const int s  = blockIdx.x;
    const int hv = blockIdx.y;
    const int d  = threadIdx.x;

    float x = core[((size_t)s * HV_ + hv) * DV_ + d];
    float ss = x * x;
#pragma unroll
    for (int m = 1; m < 64; m <<= 1) ss += __shfl_xor(ss, m);
    __shared__ float red[2];
    int wid = threadIdx.x >> 6;
    if ((threadIdx.x & 63) == 0) red[wid] = ss;
    __syncthreads();
    float var = (red[0] + red[1]) * (1.f / 128.f);
    float rs  = rsqrtf(var + EPS_);

    float z  = qkvz[(size_t)s * QKVZ_N + (hv >> 1) * 768 + 512 + (hv & 1) * 128 + d];
    float sz = z / (1.f + expf(-z));

    float y = x * rs * nw[d] * sz;
    nh[(size_t)s * VAL_DIM_ + hv * DV_ + d] = f2bf(y);
}

// ---------------------------------------------------------------------------
// launch
// ---------------------------------------------------------------------------
extern "C" void kernel_launch(void* const* d_in, const int* in_sizes, int n_in,
                              void* d_out, int out_size, void* d_ws, size_t ws_size,
                              hipStream_t stream) {
    const float* hidden  = (const float*)d_in[0];
    const float* W_qkvz  = (const float*)d_in[1];
    const float* W_ba    = (const float*)d_in[2];
    const float* conv_w  = (const float*)d_in[3];
    const float* dt_bias = (const float*)d_in[4];
    const float* A_log   = (const float*)d_in[5];
    const float* norm_w  = (const float*)d_in[6];
    const float* W_out   = (const float*)d_in[7];
    float* out = (float*)d_out;

    char* w = (char*)d_ws;
    auto alloc = [&](size_t bytes) { char* p = w; w += (bytes + 255) & ~(size_t)255; return p; };

    float*    qkvz = (float*)alloc((size_t)S_ * QKVZ_N * 4);
    float*    ba   = (float*)alloc((size_t)S_ * 32 * 4);
    float*    qc   = (float*)alloc((size_t)SPAD_ * KEY_DIM_ * 4);
    float*    kc   = (float*)alloc((size_t)SPAD_ * KEY_DIM_ * 4);
    float*    vc   = (float*)alloc((size_t)SPAD_ * VAL_DIM_ * 4);
    float*    scal = (float*)alloc((size_t)HV_ * SPAD_ * 16 * 4);
    float*    core = (float*)alloc((size_t)S_ * VAL_DIM_ * 4);
    ushort_t* hidh = (ushort_t*)alloc((size_t)S_ * D_ * 2);
    ushort_t* nrmh = (ushort_t*)alloc((size_t)S_ * VAL_DIM_ * 2);
    ushort_t* Wqh  = (ushort_t*)alloc((size_t)D_ * QKVZ_N * 2);
    ushort_t* Woh  = (ushort_t*)alloc((size_t)VAL_DIM_ * D_ * 2);

    // 0. fused prep: hidden->bf16, both weight transposes, ba
    prep_kernel<<<dim3(5632), 256, 0, stream>>>(hidden, W_qkvz, W_out, W_ba,
                                                hidh, Wqh, Woh, ba);

    // 1. qkvz = hidden @ W_qkvz
    gemm_bf16<64, 128, 1, 4><<<dim3(QKVZ_N / 128, S_ / 64), 256, 0, stream>>>(
        hidh, Wqh, qkvz, S_, QKVZ_N, D_);

    // 2. conv + silu + l2norm
    conv_kernel<<<dim3(S_, 32), 128, 0, stream>>>(qkvz, conv_w, qc, kc, vc);

    // 3. lookahead scalars (gating fused)
    scal_kernel<<<dim3(S_), 256, 0, stream>>>(kc, qc, ba, A_log, dt_bias, scal);

    // 4. scan (R6 structure + conflict-free b128 row partition)
    scan_kernel<<<dim3(DV_ / 8, HV_), 128, 0, stream>>>(qc, kc, vc, scal, core);

    // 5. RMS norm + gate -> bf16
    normgate_kernel<<<dim3(S_, HV_), 128, 0, stream>>>(core, qkvz, norm_w, nrmh);

    // 6. out = nrm @ W_out
    gemm_bf16<64, 64, 2, 2><<<dim3(D_ / 64, S_ / 64), 256, 0, stream>>>(
        nrmh, Woh, out, S_, D_, VAL_DIM_);
}